// Round 10
// baseline (239.144 us; speedup 1.0000x reference)
//
#include <hip/hip_runtime.h>
#include <cstdint>

#define BATCH 2
#define SEQ   2048
#define EMB   1024
#define NHEAD 16
#define HDIM  64
#define NTOK  (BATCH*SEQ)

typedef __attribute__((ext_vector_type(8))) short bf16x8;
typedef __attribute__((ext_vector_type(8))) short short8;
typedef __attribute__((ext_vector_type(4))) float f32x4;

__device__ inline unsigned short f2bf(float f) {
    unsigned u = __float_as_uint(f);
    u += 0x7FFF + ((u >> 16) & 1);          // RNE
    return (unsigned short)(u >> 16);
}

__device__ inline unsigned cvt_pk_bf16(float lo, float hi) {
    unsigned r;
    asm("v_cvt_pk_bf16_f32 %0, %1, %2" : "=v"(r) : "v"(lo), "v"(hi));
    return r;
}

__device__ inline void gload16(const void* g, void* lds) {
    __builtin_amdgcn_global_load_lds(
        (const __attribute__((address_space(1))) unsigned int*)g,
        (__attribute__((address_space(3))) unsigned int*)lds, 16, 0, 0);
}

// ---------------------------------------------------------------------------
// x fp32 -> bf16
__global__ __launch_bounds__(256)
void conv_x(const float* __restrict__ x, unsigned short* __restrict__ xb) {
    int i = (blockIdx.x * 256 + threadIdx.x) * 8;
    float4 a = *(const float4*)(x + i);
    float4 b = *(const float4*)(x + i + 4);
    short8 o;
    o[0]=f2bf(a.x); o[1]=f2bf(a.y); o[2]=f2bf(a.z); o[3]=f2bf(a.w);
    o[4]=f2bf(b.x); o[5]=f2bf(b.y); o[6]=f2bf(b.z); o[7]=f2bf(b.w);
    *(short8*)(xb + i) = o;
}

// W[k][n] fp32 -> Wt[n][k] bf16 (4 matrices, z-indexed), 64x64 tiles via LDS
__global__ __launch_bounds__(256)
void conv_wt(const float* __restrict__ Wq, const float* __restrict__ Wk,
             const float* __restrict__ Wv, const float* __restrict__ Wo,
             unsigned short* __restrict__ Wt) {
    const float* W = blockIdx.z==0?Wq : blockIdx.z==1?Wk : blockIdx.z==2?Wv : Wo;
    unsigned short* out = Wt + (size_t)blockIdx.z * EMB * EMB;
    __shared__ float T[64][68];
    const int t = threadIdx.x;
    const int k0 = blockIdx.x * 64, n0 = blockIdx.y * 64;
    #pragma unroll
    for (int rr = 0; rr < 4; ++rr) {
        int row = (t >> 4) + 16 * rr;
        float4 v = *(const float4*)(W + (size_t)(k0+row)*EMB + n0 + (t&15)*4);
        *(float4*)&T[row][(t&15)*4] = v;
    }
    __syncthreads();
    #pragma unroll
    for (int it = 0; it < 2; ++it) {
        int ci = it*256 + t;
        int nr = ci >> 3, kc = ci & 7;
        short8 o;
        #pragma unroll
        for (int j = 0; j < 8; ++j) o[j] = f2bf(T[kc*8+j][nr]);
        *(short8*)(out + (size_t)(n0+nr)*EMB + k0 + kc*8) = o;
    }
}

// V [B,S,H*D] bf16 -> Vt [B*H, D, S] bf16. 64x64 tiles, LDS stride 65.
__global__ __launch_bounds__(256)
void transpose_v(const unsigned short* __restrict__ Vb, unsigned short* __restrict__ Vt) {
    __shared__ unsigned short T[64*65];
    const int t = threadIdx.x;
    const int s0 = blockIdx.x * 64;
    const int bh = blockIdx.y;
    const int b = bh >> 4, h = bh & 15;
    const unsigned short* src = Vb + ((size_t)b*SEQ + s0)*EMB + h*HDIM;
    #pragma unroll
    for (int it = 0; it < 2; ++it) {
        int ci = it*256 + t;
        int r = ci >> 3, c = ci & 7;
        short8 v = *(const short8*)(src + (size_t)r*EMB + c*8);
        #pragma unroll
        for (int j = 0; j < 8; ++j) T[r*65 + c*8 + j] = (unsigned short)v[j];
    }
    __syncthreads();
    unsigned short* dst = Vt + (size_t)bh * HDIM * SEQ + s0;
    #pragma unroll
    for (int it = 0; it < 2; ++it) {
        int ci = it*256 + t;
        int d = ci >> 3, c = ci & 7;
        short8 o;
        #pragma unroll
        for (int j = 0; j < 8; ++j) o[j] = (short)T[(c*8 + j)*65 + d];
        *(short8*)(dst + (size_t)d*SEQ + c*8) = o;
    }
}

// ---------------------------------------------------------------------------
// Fused QKV GEMM, 128x128 tiles, BK=32, 4 waves, dbuf. Grid (24,32)=768 blocks
// (3/CU). z = bx>>3 selects Q/K/V. Q scaled by 0.125*log2(e).
__global__ __launch_bounds__(256)
void gemm_qkv(const unsigned short* __restrict__ xb, const unsigned short* __restrict__ Wt,
              const float* __restrict__ bq, const float* __restrict__ bk,
              const float* __restrict__ bv,
              unsigned short* __restrict__ Qb, unsigned short* __restrict__ Kb,
              unsigned short* __restrict__ Vb) {
    const int bx = blockIdx.x;
    const int z = bx >> 3;
    const unsigned short* W = Wt + (size_t)z * EMB * EMB;
    const float* bias = z==0 ? bq : z==1 ? bk : bv;
    unsigned short* out = z==0 ? Qb : z==1 ? Kb : Vb;
    const float scale = z==0 ? (0.125f * 1.44269504f) : 1.0f;
    const int nL = (bx & 7) * 128;

    __shared__ __align__(16) unsigned short As[2][128*32];
    __shared__ __align__(16) unsigned short Bs[2][128*32];

    const int tid = threadIdx.x, lane = tid & 63, wid = tid >> 6;
    const int m0 = blockIdx.y * 128;
    const int wr = wid >> 1, wc = wid & 1;

    const int ci0 = tid, ci1 = 256 + tid;
    const int row0 = ci0 >> 2, c0 = (ci0 & 3) ^ ((row0 >> 1) & 3);
    const int row1 = ci1 >> 2, c1 = (ci1 & 3) ^ ((row1 >> 1) & 3);
    const int dst0 = wid*64, dst1 = 256 + wid*64;

    f32x4 acc[4][4];
    #pragma unroll
    for (int i = 0; i < 4; ++i)
        #pragma unroll
        for (int j = 0; j < 4; ++j) acc[i][j] = f32x4{0.f,0.f,0.f,0.f};

    gload16(xb + (size_t)(m0+row0)*EMB + c0*8, (char*)As[0] + dst0*16);
    gload16(W  + (size_t)(nL+row0)*EMB + c0*8, (char*)Bs[0] + dst0*16);
    gload16(xb + (size_t)(m0+row1)*EMB + c1*8, (char*)As[0] + dst1*16);
    gload16(W  + (size_t)(nL+row1)*EMB + c1*8, (char*)Bs[0] + dst1*16);
    __syncthreads();

    for (int kk = 0; kk < EMB/32; ++kk) {
        const int cur = kk & 1;
        if (kk < EMB/32 - 1) {
            int k0 = (kk+1) * 32;
            gload16(xb + (size_t)(m0+row0)*EMB + k0 + c0*8, (char*)As[cur^1] + dst0*16);
            gload16(W  + (size_t)(nL+row0)*EMB + k0 + c0*8, (char*)Bs[cur^1] + dst0*16);
            gload16(xb + (size_t)(m0+row1)*EMB + k0 + c1*8, (char*)As[cur^1] + dst1*16);
            gload16(W  + (size_t)(nL+row1)*EMB + k0 + c1*8, (char*)Bs[cur^1] + dst1*16);
        }
        bf16x8 af[4], bf[4];
        #pragma unroll
        for (int i = 0; i < 4; ++i) {
            int ar = 64*wr + 16*i + (lane & 15);
            int ac = (lane >> 4) ^ ((ar >> 1) & 3);
            af[i] = *(const bf16x8*)((const char*)As[cur] + ar*64 + ac*16);
            int br = 64*wc + 16*i + (lane & 15);
            int bc = (lane >> 4) ^ ((br >> 1) & 3);
            bf[i] = *(const bf16x8*)((const char*)Bs[cur] + br*64 + bc*16);
        }
        #pragma unroll
        for (int i = 0; i < 4; ++i)
            #pragma unroll
            for (int j = 0; j < 4; ++j)
                acc[i][j] = __builtin_amdgcn_mfma_f32_16x16x32_bf16(af[i], bf[j], acc[i][j], 0, 0, 0);
        __syncthreads();
    }

    #pragma unroll
    for (int j = 0; j < 4; ++j) {
        int col = nL + 64*wc + 16*j + (lane & 15);
        float bvv = bias[col];
        #pragma unroll
        for (int i = 0; i < 4; ++i) {
            int rw0 = m0 + 64*wr + 16*i + (lane >> 4) * 4;
            #pragma unroll
            for (int r = 0; r < 4; ++r)
                out[(size_t)(rw0+r)*EMB + col] = f2bf((acc[i][j][r] + bvv) * scale);
        }
    }
}

// ---------------------------------------------------------------------------
// Final projection, 128x128 tiles, BK=32, 4 waves, dbuf, SPLIT-K=2.
// Grid (8,32,2)=512 blocks (2/CU). d_out is pre-zeroed; fp32 atomicAdd;
// bias folded into split 0.
__global__ __launch_bounds__(256)
void gemm_out(const unsigned short* __restrict__ Cb, const unsigned short* __restrict__ Wto,
              const float* __restrict__ bo, float* __restrict__ out) {
    __shared__ __align__(16) unsigned short As[2][128*32];
    __shared__ __align__(16) unsigned short Bs[2][128*32];

    const int tid = threadIdx.x, lane = tid & 63, wid = tid >> 6;
    const int m0 = blockIdx.y * 128, n0 = blockIdx.x * 128;
    const int kb = blockIdx.z * (EMB/2);
    const int wr = wid >> 1, wc = wid & 1;

    const int ci0 = tid, ci1 = 256 + tid;
    const int row0 = ci0 >> 2, c0 = (ci0 & 3) ^ ((row0 >> 1) & 3);
    const int row1 = ci1 >> 2, c1 = (ci1 & 3) ^ ((row1 >> 1) & 3);
    const int dst0 = wid*64, dst1 = 256 + wid*64;

    f32x4 acc[4][4];
    #pragma unroll
    for (int i = 0; i < 4; ++i)
        #pragma unroll
        for (int j = 0; j < 4; ++j) acc[i][j] = f32x4{0.f,0.f,0.f,0.f};

    gload16(Cb  + (size_t)(m0+row0)*EMB + kb + c0*8, (char*)As[0] + dst0*16);
    gload16(Wto + (size_t)(n0+row0)*EMB + kb + c0*8, (char*)Bs[0] + dst0*16);
    gload16(Cb  + (size_t)(m0+row1)*EMB + kb + c1*8, (char*)As[0] + dst1*16);
    gload16(Wto + (size_t)(n0+row1)*EMB + kb + c1*8, (char*)Bs[0] + dst1*16);
    __syncthreads();

    for (int kk = 0; kk < EMB/64; ++kk) {       // 16 steps of BK=32 over K/2
        const int cur = kk & 1;
        if (kk < EMB/64 - 1) {
            int k0 = kb + (kk+1) * 32;
            gload16(Cb  + (size_t)(m0+row0)*EMB + k0 + c0*8, (char*)As[cur^1] + dst0*16);
            gload16(Wto + (size_t)(n0+row0)*EMB + k0 + c0*8, (char*)Bs[cur^1] + dst0*16);
            gload16(Cb  + (size_t)(m0+row1)*EMB + k0 + c1*8, (char*)As[cur^1] + dst1*16);
            gload16(Wto + (size_t)(n0+row1)*EMB + k0 + c1*8, (char*)Bs[cur^1] + dst1*16);
        }
        bf16x8 af[4], bf[4];
        #pragma unroll
        for (int i = 0; i < 4; ++i) {
            int ar = 64*wr + 16*i + (lane & 15);
            int ac = (lane >> 4) ^ ((ar >> 1) & 3);
            af[i] = *(const bf16x8*)((const char*)As[cur] + ar*64 + ac*16);
            int br = 64*wc + 16*i + (lane & 15);
            int bc = (lane >> 4) ^ ((br >> 1) & 3);
            bf[i] = *(const bf16x8*)((const char*)Bs[cur] + br*64 + bc*16);
        }
        #pragma unroll
        for (int i = 0; i < 4; ++i)
            #pragma unroll
            for (int j = 0; j < 4; ++j)
                acc[i][j] = __builtin_amdgcn_mfma_f32_16x16x32_bf16(af[i], bf[j], acc[i][j], 0, 0, 0);
        __syncthreads();
    }

    const bool first = (blockIdx.z == 0);
    #pragma unroll
    for (int j = 0; j < 4; ++j) {
        int col = n0 + 64*wc + 16*j + (lane & 15);
        float bvv = first ? bo[col] : 0.0f;
        #pragma unroll
        for (int i = 0; i < 4; ++i) {
            int rw0 = m0 + 64*wr + 16*i + (lane >> 4) * 4;
            #pragma unroll
            for (int r = 0; r < 4; ++r)
                atomicAdd(&out[(size_t)(rw0+r)*EMB + col], acc[i][j][r] + bvv);
        }
    }
}

// ---------------------------------------------------------------------------
// MFMA flash attention: QBLK=64, swapped QK^T, no-max softmax (log2 units),
// dbuf K/V^T via global_load_lds, 1 barrier/tile. P-exchange via
// permlane16/32_swap (VALU) instead of ds_bpermute (DS pipe).
__global__ __launch_bounds__(256, 4)
void attn(const unsigned short* __restrict__ Qg, const unsigned short* __restrict__ Kg,
          const unsigned short* __restrict__ Vt, unsigned short* __restrict__ Cg) {
    __shared__ __align__(16) unsigned short Ks[2][64*64];
    __shared__ __align__(16) unsigned short Vs[2][64*64];

    const int tid = threadIdx.x, lane = tid & 63, wid = tid >> 6;
    const int qb = blockIdx.x, bh = blockIdx.y;
    const int b = bh >> 4, h = bh & 15;
    const size_t base = (size_t)b * SEQ * EMB + (size_t)h * HDIM;
    const unsigned short* Qp = Qg + base + (size_t)qb * 64 * EMB;
    const unsigned short* Kp = Kg + base;
    const unsigned short* Vtp = Vt + (size_t)bh * HDIM * SEQ;   // [d][S]

    #pragma unroll
    for (int it = 0; it < 2; ++it) {
        int ci = it*256 + tid, row = ci >> 3, c = (ci & 7) ^ (row & 7);
        gload16(Qp + (size_t)row*EMB + c*8, (char*)Ks[0] + (it*256 + wid*64)*16);
    }
    __syncthreads();
    bf16x8 qf[2];
    #pragma unroll
    for (int kc = 0; kc < 2; ++kc) {
        int r = 16*wid + (lane & 15);
        int c = ((lane >> 4) + 4*kc) ^ (r & 7);
        qf[kc] = *(const bf16x8*)((const char*)Ks[0] + r*128 + c*16);
    }
    __syncthreads();

    #pragma unroll
    for (int it = 0; it < 2; ++it) {
        int ci = it*256 + tid, row = ci >> 3, c = (ci & 7) ^ (row & 7);
        gload16(Kp + (size_t)row*EMB + c*8, (char*)Ks[0] + (it*256 + wid*64)*16);
        gload16(Vtp + (size_t)row*SEQ + c*8, (char*)Vs[0] + (it*256 + wid*64)*16);
    }
    __syncthreads();

    f32x4 O[4];
    #pragma unroll
    for (int j = 0; j < 4; ++j) O[j] = f32x4{0.f,0.f,0.f,0.f};
    float l_run = 0.f;

    for (int kt = 0; kt < SEQ/64; ++kt) {
        const int cur = kt & 1, nxt = cur ^ 1;
        if (kt < SEQ/64 - 1) {
            const unsigned short* Kt = Kp + (size_t)(kt+1)*64*EMB;
            const unsigned short* Vn = Vtp + (size_t)(kt+1)*64;
            #pragma unroll
            for (int it = 0; it < 2; ++it) {
                int ci = it*256 + tid, row = ci >> 3, c = (ci & 7) ^ (row & 7);
                gload16(Kt + (size_t)row*EMB + c*8, (char*)Ks[nxt] + (it*256 + wid*64)*16);
                gload16(Vn + (size_t)row*SEQ + c*8, (char*)Vs[nxt] + (it*256 + wid*64)*16);
            }
        }

        // ---- swapped QK^T ----
        f32x4 s[4];
        __builtin_amdgcn_s_setprio(1);
        #pragma unroll
        for (int nk = 0; nk < 4; ++nk) {
            s[nk] = f32x4{0.f,0.f,0.f,0.f};
            #pragma unroll
            for (int kc = 0; kc < 2; ++kc) {
                int r = 16*nk + (lane & 15);
                int c = ((lane >> 4) + 4*kc) ^ (r & 7);
                bf16x8 kf = *(const bf16x8*)((const char*)Ks[cur] + r*128 + c*16);
                s[nk] = __builtin_amdgcn_mfma_f32_16x16x32_bf16(kf, qf[kc], s[nk], 0, 0, 0);
            }
        }
        __builtin_amdgcn_s_setprio(0);

        // ---- softmax without max-shift: p = 2^s ----
        float psv[4];
        #pragma unroll
        for (int nk = 0; nk < 4; ++nk) {
            #pragma unroll
            for (int r = 0; r < 4; ++r)
                s[nk][r] = exp2f(s[nk][r]);
            psv[nk] = (s[nk][0] + s[nk][1]) + (s[nk][2] + s[nk][3]);
        }
        float ps = (psv[0] + psv[1]) + (psv[2] + psv[3]);
        ps += __shfl_xor(ps, 16);
        ps += __shfl_xor(ps, 32);
        l_run += ps;

        // ---- pack P -> bf16; redistribute via permlane swaps (VALU) ----
        // u[0]={A0,A2,C0,C2}, u[2]={A1,A3,C1,C3} from A=pk[2kc][0], C=pk[2kc+1][0]
        // via p32swap then p16swap; same for (B,D) -> u[1],u[3].
        unsigned pk[4][2];
        #pragma unroll
        for (int nk = 0; nk < 4; ++nk) {
            pk[nk][0] = cvt_pk_bf16(s[nk][0], s[nk][1]);
            pk[nk][1] = cvt_pk_bf16(s[nk][2], s[nk][3]);
        }
        bf16x8 pf[2];
        #pragma unroll
        for (int kc = 0; kc < 2; ++kc) {
            unsigned x0 = pk[2*kc][0],   y0 = pk[2*kc+1][0];
            unsigned x1 = pk[2*kc][1],   y1 = pk[2*kc+1][1];
            asm("v_permlane32_swap_b32 %0, %1" : "+v"(x0), "+v"(y0));
            asm("v_permlane16_swap_b32 %0, %1" : "+v"(x0), "+v"(y0));
            asm("v_permlane32_swap_b32 %0, %1" : "+v"(x1), "+v"(y1));
            asm("v_permlane16_swap_b32 %0, %1" : "+v"(x1), "+v"(y1));
            union { unsigned u[4]; bf16x8 v; } cvt;
            cvt.u[0] = x0; cvt.u[1] = x1; cvt.u[2] = y0; cvt.u[3] = y1;
            pf[kc] = cvt.v;
        }

        // ---- PV ----
        __builtin_amdgcn_s_setprio(1);
        #pragma unroll
        for (int jd = 0; jd < 4; ++jd) {
            #pragma unroll
            for (int kc = 0; kc < 2; ++kc) {
                int d = 16*jd + (lane & 15);
                int c = ((lane >> 4) + 4*kc) ^ (d & 7);
                bf16x8 vf = *(const bf16x8*)((const char*)Vs[cur] + d*128 + c*16);
                O[jd] = __builtin_amdgcn_mfma_f32_16x16x32_bf16(pf[kc], vf, O[jd], 0, 0, 0);
            }
        }
        __builtin_amdgcn_s_setprio(0);
        __syncthreads();
    }

    // ---- epilogue ----
    float inv[4];
    #pragma unroll
    for (int r = 0; r < 4; ++r) inv[r] = 1.f / __shfl(l_run, (lane >> 4)*4 + r);
    unsigned short* Cp = Cg + base + (size_t)qb * 64 * EMB;
    #pragma unroll
    for (int jd = 0; jd < 4; ++jd)
        #pragma unroll
        for (int r = 0; r < 4; ++r) {
            int row = 16*wid + (lane >> 4)*4 + r;
            int col = 16*jd + (lane & 15);
            Cp[(size_t)row*EMB + col] = f2bf(O[jd][r] * inv[r]);
        }
}

// ---------------------------------------------------------------------------
extern "C" void kernel_launch(void* const* d_in, const int* in_sizes, int n_in,
                              void* d_out, int out_size, void* d_ws, size_t ws_size,
                              hipStream_t stream) {
    const float* x  = (const float*)d_in[0];
    const float* Wq = (const float*)d_in[1];
    const float* bq = (const float*)d_in[2];
    const float* Wk = (const float*)d_in[3];
    const float* bk = (const float*)d_in[4];
    const float* Wv = (const float*)d_in[5];
    const float* bv = (const float*)d_in[6];
    const float* Wo = (const float*)d_in[7];
    const float* bo = (const float*)d_in[8];
    float* out = (float*)d_out;

    unsigned short* xb = (unsigned short*)d_ws;                 // 8 MB
    unsigned short* Wt = xb + (size_t)NTOK * EMB;               // 8 MB (4 mats)
    unsigned short* Qb = Wt + (size_t)4 * EMB * EMB;            // 8 MB
    unsigned short* Kb = Qb + (size_t)NTOK * EMB;               // 8 MB
    unsigned short* Vb = Kb + (size_t)NTOK * EMB;               // 8 MB
    unsigned short* Cb = Vb + (size_t)NTOK * EMB;               // 8 MB
    unsigned short* Vtr = Cb + (size_t)NTOK * EMB;              // 8 MB

    hipMemsetAsync(out, 0, (size_t)out_size * sizeof(float), stream);
    conv_x<<<dim3((NTOK*EMB)/(256*8)), 256, 0, stream>>>(x, xb);
    conv_wt<<<dim3(16, 16, 4), 256, 0, stream>>>(Wq, Wk, Wv, Wo, Wt);
    gemm_qkv<<<dim3(24, 32), 256, 0, stream>>>(xb, Wt, bq, bk, bv, Qb, Kb, Vb);
    transpose_v<<<dim3(SEQ/64, BATCH*NHEAD), 256, 0, stream>>>(Vb, Vtr);
    attn<<<dim3(SEQ/64, BATCH*NHEAD), 256, 0, stream>>>(Qb, Kb, Vtr, Cb);
    gemm_out<<<dim3(EMB/128, NTOK/128, 2), 256, 0, stream>>>(Cb, Wt + (size_t)3*EMB*EMB, bo, out);
}